// Round 9
// baseline (144.177 us; speedup 1.0000x reference)
//
#include <hip/hip_runtime.h>

// PolynomialAttn: B=2,H=16,S=2048,D=64, degree=2, eps=1e-4, fp32 in/out.
// v17: 8-phase-template port. All seven prior structures (register streams,
// LDS 2-barrier, skew, stagger, chain-split) plateau at 24-26% MfmaUtil --
// numerically the known 2-phase plateau (m233: 24% of peak; escape = fine
// phase interleave with counted vmcnt + setprio, 62% on GEMM; T2/T5 null
// outside it). v17: 512 thr / 8 waves (1 strip x e-half each), 4-slot LDS
// ring via global_load_lds (2x1KB per wave/tile), 4 phases/tile:
// {ds_read ops || stage; barrier; lgkmcnt(0); sched_barrier; setprio(1);
//  2-MFMA cluster; setprio(0); barrier}; PV-b skewed into next tile's Ph1;
// vmcnt(2) once per tile (never 0 mid-loop). Epilogue aliases the ring.

#define S_LEN 2048
#define DH    64
#define BQ    128
#define BK    64
#define EPSTR 68        // epilogue fp32 stride
#define PSTR  65        // prepass V-transpose LDS stride
#define BH_N  32        // B*H
#define PER_BH (S_LEN * DH)   // 131072 elems
#define NT    (S_LEN / BK)    // 32 KV tiles
#define SLOT  16384           // one KV tile in LDS: K 8KB + V 8KB
#define SMEM_BYTES 70656      // max(4*SLOT ring=65536, epb 69632 + dbuf 1024)

typedef __bf16 bf16x8 __attribute__((ext_vector_type(8)));
typedef __bf16 bf16x2 __attribute__((ext_vector_type(2)));
typedef float  f32x2  __attribute__((ext_vector_type(2)));
typedef float  f32x4  __attribute__((ext_vector_type(4)));
typedef float  f32x16 __attribute__((ext_vector_type(16)));
typedef unsigned int uivec2 __attribute__((ext_vector_type(2)));

__device__ __forceinline__ unsigned short f2bf(float f) {
    union { float f; unsigned int u; } x; x.f = f;
    unsigned int u = x.u;
    return (unsigned short)((u + 0x7fffu + ((u >> 16) & 1u)) >> 16);  // RNE
}

__device__ __forceinline__ unsigned int pack2bf(float lo, float hi) {
#if __has_builtin(__builtin_amdgcn_cvt_pk_bf16_f32)
    bf16x2 p = __builtin_amdgcn_cvt_pk_bf16_f32(lo, hi);
    union { bf16x2 v; unsigned int u; } c; c.v = p;
    return c.u;
#else
    return (unsigned int)f2bf(lo) | ((unsigned int)f2bf(hi) << 16);
#endif
}

__device__ __forceinline__ void pl32swap(unsigned int& a, unsigned int& b) {
#if __has_builtin(__builtin_amdgcn_permlane32_swap)
    uivec2 r = __builtin_amdgcn_permlane32_swap(a, b, false, false);
    a = r[0]; b = r[1];
#else
    asm("v_permlane32_swap_b32 %0, %1" : "+v"(a), "+v"(b));
#endif
}

// DMA 16B/lane global->LDS (lds dest = wave-uniform base + lane*16, linear).
__device__ __forceinline__ void dma16(const void* g, void* l) {
    __builtin_amdgcn_global_load_lds(
        (const __attribute__((address_space(1))) unsigned int*)g,
        (__attribute__((address_space(3))) unsigned int*)l, 16, 0, 0);
}

// ---------------- prepass: K -> fragment-order bf16, V -> V^T fragment-order bf16 ----
// Kf layout (ushorts): [bh][t][e][ks][lane]*8 ; lane(l31,h) holds
//   K[bh][64t + 32e + l31][16ks + 8h + 0..7]
// Vf layout (ushorts): [bh][t][e][ksl][mt][lane]*8 ; lane(l31,h) holds
//   V^T[bh][mt*32 + l31][64t + 32e + 16ksl + 8h + 0..7]
__global__ __launch_bounds__(256)
void prepass_kernel(const float* __restrict__ kg, const float* __restrict__ vg,
                    unsigned short* __restrict__ kfo, unsigned short* __restrict__ vfo)
{
    __shared__ unsigned short Lk[64 * 72];
    __shared__ unsigned short Lv[64 * PSTR];
    const int tid = threadIdx.x;
    const int bh  = blockIdx.y;
    const int t   = blockIdx.x;
    const size_t base = (size_t)bh * PER_BH + (size_t)t * 64 * DH;

    const float4* kf4 = (const float4*)(kg + base);
    const float4* vf4 = (const float4*)(vg + base);
    #pragma unroll
    for (int r = 0; r < 4; ++r) {
        int idx = r * 256 + tid;              // float4 index in 64x64 tile
        int row = idx >> 4, c4 = idx & 15;
        float4 f = kf4[idx];
        ushort4 hh;
        hh.x = f2bf(f.x); hh.y = f2bf(f.y); hh.z = f2bf(f.z); hh.w = f2bf(f.w);
        *(ushort4*)&Lk[row * 72 + c4 * 4] = hh;
        float4 g = vf4[idx];
        unsigned short* pv = &Lv[row * PSTR + c4 * 4];
        pv[0] = f2bf(g.x); pv[1] = f2bf(g.y); pv[2] = f2bf(g.z); pv[3] = f2bf(g.w);
    }
    __syncthreads();

    unsigned short* kout = kfo + (size_t)bh * PER_BH + (size_t)t * 4096;
    #pragma unroll
    for (int r = 0; r < 2; ++r) {
        int pos = r * 256 + tid;
        int lam = pos & 63, rest = pos >> 6;
        int e = rest >> 2, ks = rest & 3;
        int l31 = lam & 31, h = lam >> 5;
        uint4 v = *(const uint4*)&Lk[(e * 32 + l31) * 72 + ks * 16 + h * 8];
        *(uint4*)(kout + (size_t)pos * 8) = v;
    }
    unsigned short* vout = vfo + (size_t)bh * PER_BH + (size_t)t * 4096;
    #pragma unroll
    for (int r = 0; r < 2; ++r) {
        int pos = r * 256 + tid;
        int lam = pos & 63, rest = pos >> 6;
        int e = rest >> 2, ksl = (rest >> 1) & 1, mt = rest & 1;
        int l31 = lam & 31, h = lam >> 5;
        int d  = mt * 32 + l31;
        int j0 = e * 32 + ksl * 16 + h * 8;
        union { unsigned short s[8]; uint4 u; } u;
        #pragma unroll
        for (int jj = 0; jj < 8; ++jj) u.s[jj] = Lv[(j0 + jj) * PSTR + d];
        *(uint4*)(vout + (size_t)pos * 8) = u.u;
    }
}

// ---------------- main kernel: 8-wave, 4-slot ring, fine-phase interleave --------
__global__ __launch_bounds__(512, 4)
void poly_attn_main(const float* __restrict__ qg,
                    const unsigned short* __restrict__ kfo,
                    const unsigned short* __restrict__ vfo,
                    float* __restrict__ og)
{
    __shared__ __align__(16) unsigned char smem[SMEM_BYTES];

    const int tid  = threadIdx.x;
    const int lane = tid & 63;
    const int w    = tid >> 6;    // 0..7
    const int sp   = w >> 1;      // strip: Q rows [32sp, 32sp+32)
    const int e    = w & 1;       // j-half of each KV tile
    const int l31  = lane & 31;
    const int h    = lane >> 5;

    // XCD swizzle: id%8 -> XCD; 4 bh per XCD
    const int id = blockIdx.x;
    const int r5 = id & 31;
    const int bh = (r5 & 7) * 4 + (r5 >> 3);
    const int qt = id >> 5;                 // 0..15
    const int q0 = qt * BQ;

    const float* qb = qg + ((size_t)bh * S_LEN + q0) * DH;
    float* ob = og + ((size_t)bh * S_LEN + q0) * DH;

    // DMA assignment: wave w stages 1KB chunk w of the K tile and of the V tile.
    const unsigned short* gkw = kfo + (size_t)bh * PER_BH + w * 512 + (size_t)lane * 8;
    const unsigned short* gvw = vfo + (size_t)bh * PER_BH + w * 512 + (size_t)lane * 8;
    unsigned char* ldsK = smem + w * 1024;          // + slot*SLOT
    unsigned char* ldsV = smem + 8192 + w * 1024;   // + slot*SLOT

    // ds_read bases (this wave's e-half)
    const unsigned char* rdK = smem + e * 4096 + (size_t)lane * 16;          // + slot*SLOT + i*1024
    const unsigned char* rdV = smem + 8192 + e * 4096 + (size_t)lane * 16;   // + slot*SLOT + i*1024

    // ---- Q B-fragments first (their loads drain before DMA issue) ----
    bf16x8 qfrag[4];
    #pragma unroll
    for (int ks = 0; ks < 4; ++ks) {
        const float* qp = qb + (32 * sp + l31) * DH + ks * 16 + h * 8;
        float4 f0 = *(const float4*)qp;
        float4 f1 = *(const float4*)(qp + 4);
        union { unsigned int d[4]; bf16x8 v; } u;
        u.d[0] = pack2bf(f0.x, f0.y);
        u.d[1] = pack2bf(f0.z, f0.w);
        u.d[2] = pack2bf(f1.x, f1.y);
        u.d[3] = pack2bf(f1.z, f1.w);
        qfrag[ks] = u.v;
    }
    __builtin_amdgcn_sched_barrier(0);

    f32x16 oacc[2];   // [mt]
    #pragma unroll
    for (int mt = 0; mt < 2; ++mt)
        #pragma unroll
        for (int r = 0; r < 16; ++r) oacc[mt][r] = 0.f;
    f32x2 ds2; ds2[0] = 0.f; ds2[1] = 0.f;

    f32x16 zacc;
    #pragma unroll
    for (int r = 0; r < 16; ++r) zacc[r] = 0.f;
    asm volatile("" : "+v"(zacc));

    uint4 kfr0, kfr1, kfr2, kfr3, vfr0, vfr1, vfp2, vfp3;
    f32x16 acc;
    unsigned int bsv[2][4];

#define WAITVM_(N) asm volatile("s_waitcnt vmcnt(" #N ")" ::: "memory")
#define WAITVM(N) WAITVM_(N)
#define LGKM0 asm volatile("s_waitcnt lgkmcnt(0)" ::: "memory")
#define BARR  __builtin_amdgcn_s_barrier()
#define SB0   __builtin_amdgcn_sched_barrier(0)
#define PRIO1 __builtin_amdgcn_s_setprio(1)
#define PRIO0 __builtin_amdgcn_s_setprio(0)

#define XF_STAGE()                                                                  \
    {                                                                               \
        unsigned int pk[4][2];                                                      \
        _Pragma("unroll")                                                           \
        for (int g = 0; g < 4; ++g) {                                               \
            f32x2 v01, v23;                                                         \
            v01[0] = acc[4*g+0]; v01[1] = acc[4*g+1];                               \
            v23[0] = acc[4*g+2]; v23[1] = acc[4*g+3];                               \
            v01 = v01 * v01; v23 = v23 * v23;                                       \
            ds2 += v01; ds2 += v23;                                                 \
            pk[g][0] = pack2bf(v01[0], v01[1]);                                     \
            pk[g][1] = pack2bf(v23[0], v23[1]);                                     \
        }                                                                           \
        _Pragma("unroll")                                                           \
        for (int ksl = 0; ksl < 2; ++ksl) {                                         \
            unsigned int a0 = pk[2*ksl][0], b0 = pk[2*ksl+1][0];                    \
            unsigned int a1 = pk[2*ksl][1], b1 = pk[2*ksl+1][1];                    \
            pl32swap(a0, b0);                                                       \
            pl32swap(a1, b1);                                                       \
            bsv[ksl][0] = a0; bsv[ksl][1] = a1;                                     \
            bsv[ksl][2] = b0; bsv[ksl][3] = b1;                                     \
        }                                                                           \
    }

    // TILE(T): 4 fine phases. Data validity for tile T guaranteed by previous
    // tile's Ph4 vmcnt + barrier. DODMA: issue tile T+2 into slot (T+2)&3
    // (holds tile T-2, fully consumed). VMC: counted vmcnt so tile T+1's DMA
    // has landed by the end of Ph4 (2 = leave T+2's two loads in flight).
#define TILE(TT, DODMA, VMC, DOPVB)                                                 \
    {                                                                               \
        const size_t so_ = (size_t)((TT) & 3) * SLOT;                               \
        /* ---- Ph1: read kf0,kf1 | issue DMA(T+2) | PV-b(T-1) ---- */              \
        kfr0 = *(const uint4*)(rdK + so_);                                          \
        kfr1 = *(const uint4*)(rdK + so_ + 1024);                                   \
        if (DODMA) {                                                                \
            const size_t go_ = (size_t)((TT) + 2) * 4096;                           \
            const size_t sn_ = (size_t)(((TT) + 2) & 3) * SLOT;                     \
            dma16(gkw + go_, ldsK + sn_);                                           \
            dma16(gvw + go_, ldsV + sn_);                                           \
        }                                                                           \
        BARR; LGKM0; SB0; PRIO1;                                                    \
        if (DOPVB) {                                                                \
            union { unsigned int d[4]; bf16x8 v; } bu;                              \
            bu.d[0] = bsv[1][0]; bu.d[1] = bsv[1][1];                               \
            bu.d[2] = bsv[1][2]; bu.d[3] = bsv[1][3];                               \
            union { uint4 u; bf16x8 v; } vv;                                        \
            vv.u = vfp2;                                                            \
            oacc[0] = __builtin_amdgcn_mfma_f32_32x32x16_bf16(vv.v, bu.v, oacc[0], 0, 0, 0); \
            vv.u = vfp3;                                                            \
            oacc[1] = __builtin_amdgcn_mfma_f32_32x32x16_bf16(vv.v, bu.v, oacc[1], 0, 0, 0); \
        }                                                                           \
        PRIO0; BARR;                                                                \
        /* ---- Ph2: read kf2,kf3 | QK-a ---- */                                    \
        kfr2 = *(const uint4*)(rdK + so_ + 2048);                                   \
        kfr3 = *(const uint4*)(rdK + so_ + 3072);                                   \
        BARR; LGKM0; SB0; PRIO1;                                                    \
        {                                                                           \
            union { uint4 u; bf16x8 v; } kc;                                        \
            kc.u = kfr0;                                                            \
            acc = __builtin_amdgcn_mfma_f32_32x32x16_bf16(kc.v, qfrag[0], zacc, 0, 0, 0); \
            kc.u = kfr1;                                                            \
            acc = __builtin_amdgcn_mfma_f32_32x32x16_bf16(kc.v, qfrag[1], acc, 0, 0, 0); \
        }                                                                           \
        PRIO0; BARR;                                                                \
        /* ---- Ph3: read vf0,vf1 | QK-b ---- */                                    \
        vfr0 = *(const uint4*)(rdV + so_);                                          \
        vfr1 = *(const uint4*)(rdV + so_ + 1024);                                   \
        BARR; LGKM0; SB0; PRIO1;                                                    \
        {                                                                           \
            union { uint4 u; bf16x8 v; } kc;                                        \
            kc.u = kfr2;                                                            \
            acc = __builtin_amdgcn_mfma_f32_32x32x16_bf16(kc.v, qfrag[2], acc, 0, 0, 0); \
            kc.u = kfr3;                                                            \
            acc = __builtin_amdgcn_mfma_f32_32x32x16_bf16(kc.v, qfrag[3], acc, 0, 0, 0); \
        }                                                                           \
        PRIO0; BARR;                                                                \
        /* ---- Ph4: read vfp2,vfp3 | XF | vmcnt | PV-a ---- */                     \
        vfp2 = *(const uint4*)(rdV + so_ + 2048);                                   \
        vfp3 = *(const uint4*)(rdV + so_ + 3072);                                   \
        XF_STAGE();                                                                 \
        WAITVM(VMC);                                                                \
        BARR; LGKM0; SB0; PRIO1;                                                    \
        {                                                                           \
            union { unsigned int d[4]; bf16x8 v; } bu;                              \
            bu.d[0] = bsv[0][0]; bu.d[1] = bsv[0][1];                               \
            bu.d[2] = bsv[0][2]; bu.d[3] = bsv[0][3];                               \
            union { uint4 u; bf16x8 v; } vv;                                        \
            vv.u = vfr0;                                                            \
            oacc[0] = __builtin_amdgcn_mfma_f32_32x32x16_bf16(vv.v, bu.v, oacc[0], 0, 0, 0); \
            vv.u = vfr1;                                                            \
            oacc[1] = __builtin_amdgcn_mfma_f32_32x32x16_bf16(vv.v, bu.v, oacc[1], 0, 0, 0); \
        }                                                                           \
        PRIO0; BARR;                                                                \
    }

    // ---- prologue: DMA tiles 0,1; wait tile 0; barrier ----
    dma16(gkw, ldsK);
    dma16(gvw, ldsV);
    dma16(gkw + 4096, ldsK + SLOT);
    dma16(gvw + 4096, ldsV + SLOT);
    WAITVM(2);
    BARR;

    TILE(0, 1, 2, 0)
    for (int T = 1; T <= 29; ++T) {
        TILE(T, 1, 2, 1)
    }
    TILE(30, 0, 0, 1)
    TILE(31, 0, 0, 1)
    // drain: PV-b(31)
    {
        union { unsigned int d[4]; bf16x8 v; } bu;
        bu.d[0] = bsv[1][0]; bu.d[1] = bsv[1][1];
        bu.d[2] = bsv[1][2]; bu.d[3] = bsv[1][3];
        union { uint4 u; bf16x8 v; } vv;
        vv.u = vfp2;
        oacc[0] = __builtin_amdgcn_mfma_f32_32x32x16_bf16(vv.v, bu.v, oacc[0], 0, 0, 0);
        vv.u = vfp3;
        oacc[1] = __builtin_amdgcn_mfma_f32_32x32x16_bf16(vv.v, bu.v, oacc[1], 0, 0, 0);
    }
#undef TILE
#undef XF_STAGE

    // ---- denominator partial (column i = l31, this wave's j-half) ----
    float wavetot;
    { float t = ds2[0] + ds2[1]; wavetot = t + __shfl_xor(t, 32); }

    // ---- epilogue: stash partials in (re-aliased) LDS, combine, store ----
    float* epb  = (float*)smem;                 // 8 regions x 32 x EPSTR
    float* dbuf = (float*)(smem + 69632);       // 256 floats
    {
        float* ep = epb + (size_t)w * (32 * EPSTR);   // region id = w = sp*2+e
        #pragma unroll
        for (int mt = 0; mt < 2; ++mt) {
            #pragma unroll
            for (int g = 0; g < 4; ++g) {
                f32x4 vv;
                vv[0] = oacc[mt][4*g+0];
                vv[1] = oacc[mt][4*g+1];
                vv[2] = oacc[mt][4*g+2];
                vv[3] = oacc[mt][4*g+3];
                // O[i=l31][d = mt*32 + 8g + 4h + 0..3]
                *(f32x4*)&ep[l31 * EPSTR + mt * 32 + 8 * g + 4 * h] = vv;
            }
        }
        if (h == 0) dbuf[w * 32 + l31] = wavetot;
    }
    __syncthreads();

    // consumer: wave w handles rows [16w, 16w+16); lane: lr=lane>>2, quad=lane&3
    {
        const int lr   = lane >> 2;
        const int quad = lane & 3;
        const int r    = 16 * w + lr;
        const int S    = r >> 5;
        const int i    = r & 31;
        const float den = dbuf[(2 * S + 0) * 32 + i] + dbuf[(2 * S + 1) * 32 + i];
        const float inv = 1.0f / fmaxf(den, 1e-4f);
        const float* ea = epb + (size_t)(2 * S + 0) * (32 * EPSTR) + i * EPSTR;
        const float* eb = epb + (size_t)(2 * S + 1) * (32 * EPSTR) + i * EPSTR;
        #pragma unroll
        for (int it = 0; it < 4; ++it) {
            int d0 = quad * 16 + it * 4;
            f32x4 a = *(const f32x4*)&ea[d0];
            f32x4 b = *(const f32x4*)&eb[d0];
            f32x4 sm;
            sm[0] = (a[0] + b[0]) * inv;
            sm[1] = (a[1] + b[1]) * inv;
            sm[2] = (a[2] + b[2]) * inv;
            sm[3] = (a[3] + b[3]) * inv;
            *(f32x4*)&ob[(size_t)r * DH + d0] = sm;
        }
    }
}

// ---------------- fallback (self-contained, used if ws too small) ----------------
#define LSTR 72
__global__ __launch_bounds__(256, 2)
void poly_attn_fallback(const float* __restrict__ qg, const float* __restrict__ kg,
                        const float* __restrict__ vg, float* __restrict__ og)
{
    __shared__ unsigned short Qs[64 * LSTR];
    __shared__ unsigned short Ksl[64 * LSTR];
    __shared__ unsigned short Vt[64 * LSTR];
    __shared__ unsigned short Xsl[64 * LSTR];

    const int tid  = threadIdx.x;
    const int lane = tid & 63;
    const int w    = tid >> 6;
    const int c    = lane & 15;
    const int quad = lane >> 4;
    const int i0   = w * 16;

    const int bh = blockIdx.y;
    const int q0 = blockIdx.x * 64;

    const float* qb = qg + ((size_t)bh * S_LEN + q0) * DH;
    const float* kb = kg + (size_t)bh * S_LEN * DH;
    const float* vb = vg + (size_t)bh * S_LEN * DH;
    float*       ob = og + ((size_t)bh * S_LEN + q0) * DH;

    {
        const float4* qf4 = (const float4*)qb;
        #pragma unroll
        for (int r = 0; r < 4; ++r) {
            int idx = r * 256 + tid;
            int row = idx >> 4, c4 = idx & 15;
            float4 f = qf4[idx];
            ushort4 hh;
            hh.x = f2bf(f.x); hh.y = f2bf(f.y); hh.z = f2bf(f.z); hh.w = f2bf(f.w);
            *(ushort4*)&Qs[row * LSTR + c4 * 4] = hh;
        }
    }

    f32x4 oacc[4];
    #pragma unroll
    for (int t = 0; t < 4; ++t) { oacc[t][0]=0.f; oacc[t][1]=0.f; oacc[t][2]=0.f; oacc[t][3]=0.f; }
    float dsum[4] = {0.f, 0.f, 0.f, 0.f};

    for (int t0 = 0; t0 < S_LEN; t0 += 64) {
        __syncthreads();
        {
            const float4* kf4 = (const float4*)(kb + (size_t)t0 * DH);
            const float4* vf4 = (const float4*)(vb + (size_t)t0 * DH);
            #pragma unroll
            for (int r = 0; r < 4; ++r) {
                int idx = r * 256 + tid;
                int row = idx >> 4, c4 = idx & 15;
                float4 f = kf4[idx];
                ushort4 hh;
                hh.x = f2bf(f.x); hh.y = f2bf(f.y); hh.z = f2bf(f.z); hh.w = f2bf(f.w);
                *(ushort4*)&Ksl[row * LSTR + c4 * 4] = hh;
                float4 g = vf4[idx];
                int d0 = c4 * 4;
                Vt[(d0 + 0) * LSTR + row] = f2bf(g.x);
                Vt[(d0 + 1) * LSTR + row] = f2bf(g.y);
                Vt[(d0 + 2) * LSTR + row] = f2bf(g.z);
                Vt[(d0 + 3) * LSTR + row] = f2bf(g.w);
            }
        }
        __syncthreads();

        f32x4 xacc[4];
        #pragma unroll
        for (int t = 0; t < 4; ++t) { xacc[t][0]=0.f; xacc[t][1]=0.f; xacc[t][2]=0.f; xacc[t][3]=0.f; }
        #pragma unroll
        for (int k0 = 0; k0 < 64; k0 += 32) {
            bf16x8 af = *(const bf16x8*)&Qs[(i0 + c) * LSTR + k0 + quad * 8];
            #pragma unroll
            for (int tn = 0; tn < 4; ++tn) {
                bf16x8 bfg = *(const bf16x8*)&Ksl[(tn * 16 + c) * LSTR + k0 + quad * 8];
                xacc[tn] = __builtin_amdgcn_mfma_f32_16x16x32_bf16(af, bfg, xacc[tn], 0, 0, 0);
            }
        }
        #pragma unroll
        for (int tn = 0; tn < 4; ++tn)
            #pragma unroll
            for (int r = 0; r < 4; ++r) {
                float xv = xacc[tn][r];
                float xs = xv * xv;
                dsum[r] += xs;
                Xsl[(i0 + quad * 4 + r) * LSTR + tn * 16 + c] = f2bf(xs);
            }
        __syncthreads();

        #pragma unroll
        for (int k0 = 0; k0 < 64; k0 += 32) {
            bf16x8 af = *(const bf16x8*)&Xsl[(i0 + c) * LSTR + k0 + quad * 8];
            #pragma unroll
            for (int tn = 0; tn < 4; ++tn) {
                bf16x8 bfg = *(const bf16x8*)&Vt[(tn * 16 + c) * LSTR + k0 + quad * 8];
                oacc[tn] = __builtin_amdgcn_mfma_f32_16x16x32_bf16(af, bfg, oacc[tn], 0, 0, 0);
            }
        }
    }

    #pragma unroll
    for (int r = 0; r < 4; ++r) {
        float s = dsum[r];
        s += __shfl_xor(s, 1);
        s += __shfl_xor(s, 2);
        s += __shfl_xor(s, 4);
        s += __shfl_xor(s, 8);
        dsum[r] = 1.0f / fmaxf(s, 1e-4f);
    }
    #pragma unroll
    for (int tn = 0; tn < 4; ++tn)
        #pragma unroll
        for (int r = 0; r < 4; ++r)
            ob[(i0 + quad * 4 + r) * DH + tn * 16 + c] = oacc[tn][r] * dsum[r];
}

extern "C" void kernel_launch(void* const* d_in, const int* in_sizes, int n_in,
                              void* d_out, int out_size, void* d_ws, size_t ws_size,
                              hipStream_t stream) {
    (void)in_sizes; (void)n_in; (void)out_size;
    const float* q = (const float*)d_in[0];
    const float* k = (const float*)d_in[1];
    const float* v = (const float*)d_in[2];
    float* o = (float*)d_out;

    const size_t elems = (size_t)BH_N * PER_BH;              // 4,194,304
    const size_t need  = 2 * elems * sizeof(unsigned short); // 16.78 MB

    if (ws_size >= need) {
        unsigned short* kfo = (unsigned short*)d_ws;
        unsigned short* vfo = kfo + elems;
        prepass_kernel<<<dim3(NT, BH_N), 256, 0, stream>>>(k, v, kfo, vfo);
        poly_attn_main<<<dim3(BH_N * S_LEN / BQ), 512, 0, stream>>>(q, kfo, vfo, o);
    } else {
        poly_attn_fallback<<<dim3(S_LEN / 64, BH_N), 256, 0, stream>>>(q, k, v, o);
    }
}

// Round 10
// 139.505 us; speedup vs baseline: 1.0335x; 1.0335x over previous
//
#include <hip/hip_runtime.h>

// PolynomialAttn: B=2,H=16,S=2048,D=64, degree=2, eps=1e-4, fp32 in/out.
// v18: register-neutral QK chain split on the v15 base (best known, 54us).
// v16's chain-split verdict was confounded by spill (WRITE 20.5MB); v17's
// 8-phase port both spilled (launch_bounds 512,4 -> 64 VGPR) and over-
// barriered. Live theory: dependent-MFMA latency D~512cyc makes the period
// = QK(4D) + PV(2D) + ~1k ~= 4k. v18 splits QK into 4 chains of depth 2
// (interleaved issue) and pays the +32 acc regs by single-buffering K and V
// (-32 regs; net zero vs v15). Body: QK(T); LOADK(T+1); PV(T-1); LOADV(T);
// XF(T) -- ~half-body load cover (~2k cyc) >> L2 latency. Stagger + skew +
// XCD swizzle retained. Spill canary: WRITE_SIZE must stay 16.4MB.

#define S_LEN 2048
#define DH    64
#define BQ    128
#define BK    64
#define EPSTR 68        // epilogue fp32 stride
#define PSTR  65        // prepass V-transpose LDS stride
#define BH_N  32        // B*H
#define PER_BH (S_LEN * DH)   // 131072 elems
#define NT    (S_LEN / BK)    // 32 KV tiles

typedef __bf16 bf16x8 __attribute__((ext_vector_type(8)));
typedef __bf16 bf16x2 __attribute__((ext_vector_type(2)));
typedef float  f32x2  __attribute__((ext_vector_type(2)));
typedef float  f32x4  __attribute__((ext_vector_type(4)));
typedef float  f32x16 __attribute__((ext_vector_type(16)));
typedef unsigned int uivec2 __attribute__((ext_vector_type(2)));

__device__ __forceinline__ unsigned short f2bf(float f) {
    union { float f; unsigned int u; } x; x.f = f;
    unsigned int u = x.u;
    return (unsigned short)((u + 0x7fffu + ((u >> 16) & 1u)) >> 16);  // RNE
}

__device__ __forceinline__ unsigned int pack2bf(float lo, float hi) {
#if __has_builtin(__builtin_amdgcn_cvt_pk_bf16_f32)
    bf16x2 p = __builtin_amdgcn_cvt_pk_bf16_f32(lo, hi);
    union { bf16x2 v; unsigned int u; } c; c.v = p;
    return c.u;
#else
    return (unsigned int)f2bf(lo) | ((unsigned int)f2bf(hi) << 16);
#endif
}

__device__ __forceinline__ void pl32swap(unsigned int& a, unsigned int& b) {
#if __has_builtin(__builtin_amdgcn_permlane32_swap)
    uivec2 r = __builtin_amdgcn_permlane32_swap(a, b, false, false);
    a = r[0]; b = r[1];
#else
    asm("v_permlane32_swap_b32 %0, %1" : "+v"(a), "+v"(b));
#endif
}

// ---------------- prepass: K -> fragment-order bf16, V -> V^T fragment-order bf16 ----
// Kf layout (ushorts): [bh][t][e][ks][lane]*8 ; lane(l31,h) holds
//   K[bh][64t + 32e + l31][16ks + 8h + 0..7]
// Vf layout (ushorts): [bh][t][e][ksl][mt][lane]*8 ; lane(l31,h) holds
//   V^T[bh][mt*32 + l31][64t + 32e + 16ksl + 8h + 0..7]
__global__ __launch_bounds__(256)
void prepass_kernel(const float* __restrict__ kg, const float* __restrict__ vg,
                    unsigned short* __restrict__ kfo, unsigned short* __restrict__ vfo)
{
    __shared__ unsigned short Lk[64 * 72];
    __shared__ unsigned short Lv[64 * PSTR];
    const int tid = threadIdx.x;
    const int bh  = blockIdx.y;
    const int t   = blockIdx.x;
    const size_t base = (size_t)bh * PER_BH + (size_t)t * 64 * DH;

    const float4* kf4 = (const float4*)(kg + base);
    const float4* vf4 = (const float4*)(vg + base);
    #pragma unroll
    for (int r = 0; r < 4; ++r) {
        int idx = r * 256 + tid;              // float4 index in 64x64 tile
        int row = idx >> 4, c4 = idx & 15;
        float4 f = kf4[idx];
        ushort4 hh;
        hh.x = f2bf(f.x); hh.y = f2bf(f.y); hh.z = f2bf(f.z); hh.w = f2bf(f.w);
        *(ushort4*)&Lk[row * 72 + c4 * 4] = hh;
        float4 g = vf4[idx];
        unsigned short* pv = &Lv[row * PSTR + c4 * 4];
        pv[0] = f2bf(g.x); pv[1] = f2bf(g.y); pv[2] = f2bf(g.z); pv[3] = f2bf(g.w);
    }
    __syncthreads();

    unsigned short* kout = kfo + (size_t)bh * PER_BH + (size_t)t * 4096;
    #pragma unroll
    for (int r = 0; r < 2; ++r) {
        int pos = r * 256 + tid;
        int lam = pos & 63, rest = pos >> 6;
        int e = rest >> 2, ks = rest & 3;
        int l31 = lam & 31, h = lam >> 5;
        uint4 v = *(const uint4*)&Lk[(e * 32 + l31) * 72 + ks * 16 + h * 8];
        *(uint4*)(kout + (size_t)pos * 8) = v;
    }
    unsigned short* vout = vfo + (size_t)bh * PER_BH + (size_t)t * 4096;
    #pragma unroll
    for (int r = 0; r < 2; ++r) {
        int pos = r * 256 + tid;
        int lam = pos & 63, rest = pos >> 6;
        int e = rest >> 2, ksl = (rest >> 1) & 1, mt = rest & 1;
        int l31 = lam & 31, h = lam >> 5;
        int d  = mt * 32 + l31;
        int j0 = e * 32 + ksl * 16 + h * 8;
        union { unsigned short s[8]; uint4 u; } u;
        #pragma unroll
        for (int jj = 0; jj < 8; ++jj) u.s[jj] = Lv[(j0 + jj) * PSTR + d];
        *(uint4*)(vout + (size_t)pos * 8) = u.u;
    }
}

// ---------------- main kernel: single-buffered streams, 4x depth-2 QK chains ------
__global__ __launch_bounds__(256, 2)
void poly_attn_main(const float* __restrict__ qg,
                    const unsigned short* __restrict__ kfo,
                    const unsigned short* __restrict__ vfo,
                    float* __restrict__ og)
{
    __shared__ float epb[8 * 32 * EPSTR];   // per (wave,strip) O^T partials
    __shared__ float dbuf[256];             // per (wave,strip) denominator partials

    const int tid  = threadIdx.x;
    const int lane = tid & 63;
    const int w    = tid >> 6;
    const int p    = w >> 1;      // pair id: Q rows [64p, 64p+64)
    const int e    = w & 1;       // j-half of each KV tile
    const int l31  = lane & 31;
    const int h    = lane >> 5;

    // XCD swizzle: id%8 -> XCD; 4 bh per XCD (K+V 2MB working set in its L2)
    const int id = blockIdx.x;
    const int r5 = id & 31;
    const int bh = (r5 & 7) * 4 + (r5 >> 3);
    const int qt = id >> 5;                 // 0..15
    const int q0 = qt * BQ;

    const float* qb = qg + ((size_t)bh * S_LEN + q0) * DH;
    const unsigned short* kw = kfo + (size_t)bh * PER_BH + e * 2048 + (size_t)lane * 8;
    const unsigned short* vw = vfo + (size_t)bh * PER_BH + e * 2048 + (size_t)lane * 8;
    float* ob = og + ((size_t)bh * S_LEN + q0) * DH;

    const int off = w * 8;                  // per-wave tile-ring stagger

#define KPTR(t) (kw + (size_t)(((t) + off) & 31) * 4096)
#define VPTR(t) (vw + (size_t)(((t) + off) & 31) * 4096)

    // ---- Q B-fragments: strip s rows 64p + 32s + l31, cols 16ks + 8h + 0..7 ----
    bf16x8 qfrag[2][4];
    #pragma unroll
    for (int s = 0; s < 2; ++s) {
        #pragma unroll
        for (int ks = 0; ks < 4; ++ks) {
            const float* qp = qb + (64 * p + 32 * s + l31) * DH + ks * 16 + h * 8;
            float4 f0 = *(const float4*)qp;
            float4 f1 = *(const float4*)(qp + 4);
            union { unsigned int d[4]; bf16x8 v; } u;
            u.d[0] = pack2bf(f0.x, f0.y);
            u.d[1] = pack2bf(f0.z, f0.w);
            u.d[2] = pack2bf(f1.x, f1.y);
            u.d[3] = pack2bf(f1.z, f1.w);
            qfrag[s][ks] = u.v;
        }
    }

    f32x16 oacc[2][2];   // [strip][mt]
    #pragma unroll
    for (int s = 0; s < 2; ++s)
        #pragma unroll
        for (int mt = 0; mt < 2; ++mt)
            #pragma unroll
            for (int r = 0; r < 16; ++r) oacc[s][mt][r] = 0.f;
    f32x2 ds2[2];
    ds2[0][0]=0.f; ds2[0][1]=0.f; ds2[1][0]=0.f; ds2[1][1]=0.f;

    // persistent opaque zero C-operand for QK chain starts
    f32x16 zacc;
    #pragma unroll
    for (int r = 0; r < 16; ++r) zacc[r] = 0.f;
    asm volatile("" : "+v"(zacc));

    uint4 kbuf[4], vbuf[4];          // single-buffered streams
    unsigned int bsv[2][2][4];       // [strip][ksl][dword] transformed B-frags

#define LOADK(T)                                                                    \
    { const unsigned short* kp_ = KPTR(T);                                          \
      _Pragma("unroll")                                                             \
      for (int x = 0; x < 4; ++x) kbuf[x] = *(const uint4*)(kp_ + x * 512); }
#define LOADV(T)                                                                    \
    { const unsigned short* vp_ = VPTR(T);                                          \
      _Pragma("unroll")                                                             \
      for (int x = 0; x < 4; ++x) vbuf[x] = *(const uint4*)(vp_ + x * 512); }

    // QK with 4 independent chains of depth 2 (2 per strip), interleaved issue.
#define QK_STAGE()                                                                  \
        f32x16 acc0, acc1;                                                          \
        {                                                                           \
            f32x16 a0B, a1B;                                                        \
            union { uint4 u; bf16x8 v; } k0, k1, k2, k3;                            \
            k0.u = kbuf[0]; k1.u = kbuf[1]; k2.u = kbuf[2]; k3.u = kbuf[3];         \
            acc0 = __builtin_amdgcn_mfma_f32_32x32x16_bf16(k0.v, qfrag[0][0], zacc, 0, 0, 0); \
            acc1 = __builtin_amdgcn_mfma_f32_32x32x16_bf16(k0.v, qfrag[1][0], zacc, 0, 0, 0); \
            a0B  = __builtin_amdgcn_mfma_f32_32x32x16_bf16(k2.v, qfrag[0][2], zacc, 0, 0, 0); \
            a1B  = __builtin_amdgcn_mfma_f32_32x32x16_bf16(k2.v, qfrag[1][2], zacc, 0, 0, 0); \
            acc0 = __builtin_amdgcn_mfma_f32_32x32x16_bf16(k1.v, qfrag[0][1], acc0, 0, 0, 0); \
            acc1 = __builtin_amdgcn_mfma_f32_32x32x16_bf16(k1.v, qfrag[1][1], acc1, 0, 0, 0); \
            a0B  = __builtin_amdgcn_mfma_f32_32x32x16_bf16(k3.v, qfrag[0][3], a0B, 0, 0, 0); \
            a1B  = __builtin_amdgcn_mfma_f32_32x32x16_bf16(k3.v, qfrag[1][3], a1B, 0, 0, 0); \
            acc0 = acc0 + a0B;                                                      \
            acc1 = acc1 + a1B;                                                      \
        }

#define PV_STAGE()                                                                  \
        _Pragma("unroll")                                                           \
        for (int s = 0; s < 2; ++s) {                                               \
            _Pragma("unroll")                                                       \
            for (int ksl = 0; ksl < 2; ++ksl) {                                     \
                union { unsigned int d[4]; bf16x8 v; } bu;                          \
                bu.d[0] = bsv[s][ksl][0]; bu.d[1] = bsv[s][ksl][1];                 \
                bu.d[2] = bsv[s][ksl][2]; bu.d[3] = bsv[s][ksl][3];                 \
                union { uint4 u; bf16x8 v; } vv;                                    \
                vv.u = vbuf[ksl * 2 + 0];                                           \
                oacc[s][0] = __builtin_amdgcn_mfma_f32_32x32x16_bf16(vv.v, bu.v, oacc[s][0], 0, 0, 0); \
                vv.u = vbuf[ksl * 2 + 1];                                           \
                oacc[s][1] = __builtin_amdgcn_mfma_f32_32x32x16_bf16(vv.v, bu.v, oacc[s][1], 0, 0, 0); \
            }                                                                       \
        }

#define XF_STAGE()                                                                  \
        _Pragma("unroll")                                                           \
        for (int s = 0; s < 2; ++s) {                                               \
            unsigned int pk[4][2];                                                  \
            _Pragma("unroll")                                                       \
            for (int g = 0; g < 4; ++g) {                                           \
                f32x2 v01, v23;                                                     \
                v01[0] = (s ? acc1 : acc0)[4*g+0]; v01[1] = (s ? acc1 : acc0)[4*g+1]; \
                v23[0] = (s ? acc1 : acc0)[4*g+2]; v23[1] = (s ? acc1 : acc0)[4*g+3]; \
                v01 = v01 * v01; v23 = v23 * v23;                                   \
                ds2[s] += v01; ds2[s] += v23;                                       \
                pk[g][0] = pack2bf(v01[0], v01[1]);                                 \
                pk[g][1] = pack2bf(v23[0], v23[1]);                                 \
            }                                                                       \
            _Pragma("unroll")                                                       \
            for (int ksl = 0; ksl < 2; ++ksl) {                                     \
                unsigned int a0 = pk[2*ksl][0], b0 = pk[2*ksl+1][0];                \
                unsigned int a1 = pk[2*ksl][1], b1 = pk[2*ksl+1][1];                \
                pl32swap(a0, b0);                                                   \
                pl32swap(a1, b1);                                                   \
                bsv[s][ksl][0] = a0; bsv[s][ksl][1] = a1;                           \
                bsv[s][ksl][2] = b0; bsv[s][ksl][3] = b1;                           \
            }                                                                       \
        }

    // ---- prologue: K(0); QK(0); K(1); V(0); XF(0) ----
    LOADK(0)
    { QK_STAGE(); LOADK(1) LOADV(0) XF_STAGE(); }

    // body T: QK(T) [frees kbuf]; K(T+1); PV(T-1) [frees vbuf]; V(T); XF(T).
    // Ring wraps modulo 32, so the T=31 prefetch lands harmlessly on tile off.
    for (int T = 1; T < NT; ++T) {
        QK_STAGE();
        LOADK(T + 1)
        PV_STAGE();
        LOADV(T)
        XF_STAGE();
    }
    { PV_STAGE(); }   // drain: PV(31)
#undef QK_STAGE
#undef PV_STAGE
#undef XF_STAGE
#undef LOADK
#undef LOADV
#undef KPTR
#undef VPTR

    // ---- denominator partials (column i = l31, this wave's j-half, per strip) ----
    float wavetot[2];
    #pragma unroll
    for (int s = 0; s < 2; ++s) {
        float t = ds2[s][0] + ds2[s][1];
        wavetot[s] = t + __shfl_xor(t, 32);
    }

    // ---- epilogue: stash partials, combine wave-pair j-halves, store ----
    #pragma unroll
    for (int s = 0; s < 2; ++s) {
        float* ep = epb + (size_t)(w * 2 + s) * (32 * EPSTR);
        #pragma unroll
        for (int mt = 0; mt < 2; ++mt) {
            #pragma unroll
            for (int g = 0; g < 4; ++g) {
                f32x4 vv;
                vv[0] = oacc[s][mt][4*g+0];
                vv[1] = oacc[s][mt][4*g+1];
                vv[2] = oacc[s][mt][4*g+2];
                vv[3] = oacc[s][mt][4*g+3];
                // O[i=l31][d = mt*32 + 8g + 4h + 0..3]
                *(f32x4*)&ep[l31 * EPSTR + mt * 32 + 8 * g + 4 * h] = vv;
            }
        }
        if (h == 0) dbuf[(w * 2 + s) * 32 + l31] = wavetot[s];
    }
    __syncthreads();

    // wave w handles output rows [32w, 32w+32): psrc = w>>1, ssrc = w&1
    const int psrc = w >> 1, ssrc = w & 1;
    const int r0 = (2 * psrc + 0) * 2 + ssrc;   // e=0 partial region
    const int r1 = (2 * psrc + 1) * 2 + ssrc;   // e=1 partial region
    const int lr = lane >> 1;
    const float den = dbuf[r0 * 32 + lr] + dbuf[r1 * 32 + lr];
    const float inv = 1.0f / fmaxf(den, 1e-4f);
    const float* ea = epb + (size_t)r0 * (32 * EPSTR) + lr * EPSTR;
    const float* eb = epb + (size_t)r1 * (32 * EPSTR) + lr * EPSTR;
    #pragma unroll
    for (int it = 0; it < 8; ++it) {
        int d0 = (lane & 1) * 32 + it * 4;
        f32x4 a = *(const f32x4*)&ea[d0];
        f32x4 b = *(const f32x4*)&eb[d0];
        f32x4 sm;
        sm[0] = (a[0] + b[0]) * inv;
        sm[1] = (a[1] + b[1]) * inv;
        sm[2] = (a[2] + b[2]) * inv;
        sm[3] = (a[3] + b[3]) * inv;
        *(f32x4*)&ob[(32 * w + lr) * DH + d0] = sm;
    }
}

// ---------------- fallback (self-contained, used if ws too small) ----------------
#define LSTR 72
__global__ __launch_bounds__(256, 2)
void poly_attn_fallback(const float* __restrict__ qg, const float* __restrict__ kg,
                        const float* __restrict__ vg, float* __restrict__ og)
{
    __shared__ unsigned short Qs[64 * LSTR];
    __shared__ unsigned short Ksl[64 * LSTR];
    __shared__ unsigned short Vt[64 * LSTR];
    __shared__ unsigned short Xsl[64 * LSTR];

    const int tid  = threadIdx.x;
    const int lane = tid & 63;
    const int w    = tid >> 6;
    const int c    = lane & 15;
    const int quad = lane >> 4;
    const int i0   = w * 16;

    const int bh = blockIdx.y;
    const int q0 = blockIdx.x * 64;

    const float* qb = qg + ((size_t)bh * S_LEN + q0) * DH;
    const float* kb = kg + (size_t)bh * S_LEN * DH;
    const float* vb = vg + (size_t)bh * S_LEN * DH;
    float*       ob = og + ((size_t)bh * S_LEN + q0) * DH;

    {
        const float4* qf4 = (const float4*)qb;
        #pragma unroll
        for (int r = 0; r < 4; ++r) {
            int idx = r * 256 + tid;
            int row = idx >> 4, c4 = idx & 15;
            float4 f = qf4[idx];
            ushort4 hh;
            hh.x = f2bf(f.x); hh.y = f2bf(f.y); hh.z = f2bf(f.z); hh.w = f2bf(f.w);
            *(ushort4*)&Qs[row * LSTR + c4 * 4] = hh;
        }
    }

    f32x4 oacc[4];
    #pragma unroll
    for (int t = 0; t < 4; ++t) { oacc[t][0]=0.f; oacc[t][1]=0.f; oacc[t][2]=0.f; oacc[t][3]=0.f; }
    float dsum[4] = {0.f, 0.f, 0.f, 0.f};

    for (int t0 = 0; t0 < S_LEN; t0 += 64) {
        __syncthreads();
        {
            const float4* kf4 = (const float4*)(kb + (size_t)t0 * DH);
            const float4* vf4 = (const float4*)(vb + (size_t)t0 * DH);
            #pragma unroll
            for (int r = 0; r < 4; ++r) {
                int idx = r * 256 + tid;
                int row = idx >> 4, c4 = idx & 15;
                float4 f = kf4[idx];
                ushort4 hh;
                hh.x = f2bf(f.x); hh.y = f2bf(f.y); hh.z = f2bf(f.z); hh.w = f2bf(f.w);
                *(ushort4*)&Ksl[row * LSTR + c4 * 4] = hh;
                float4 g = vf4[idx];
                int d0 = c4 * 4;
                Vt[(d0 + 0) * LSTR + row] = f2bf(g.x);
                Vt[(d0 + 1) * LSTR + row] = f2bf(g.y);
                Vt[(d0 + 2) * LSTR + row] = f2bf(g.z);
                Vt[(d0 + 3) * LSTR + row] = f2bf(g.w);
            }
        }
        __syncthreads();

        f32x4 xacc[4];
        #pragma unroll
        for (int t = 0; t < 4; ++t) { xacc[t][0]=0.f; xacc[t][1]=0.f; xacc[t][2]=0.f; xacc[t][3]=0.f; }
        #pragma unroll
        for (int k0 = 0; k0 < 64; k0 += 32) {
            bf16x8 af = *(const bf16x8*)&Qs[(i0 + c) * LSTR + k0 + quad * 8];
            #pragma unroll
            for (int tn = 0; tn < 4; ++tn) {
                bf16x8 bfg = *(const bf16x8*)&Ksl[(tn * 16 + c) * LSTR + k0 + quad * 8];
                xacc[tn] = __builtin_amdgcn_mfma_f32_16x16x32_bf16(af, bfg, xacc[tn], 0, 0, 0);
            }
        }
        #pragma unroll
        for (int tn = 0; tn < 4; ++tn)
            #pragma unroll
            for (int r = 0; r < 4; ++r) {
                float xv = xacc[tn][r];
                float xs = xv * xv;
                dsum[r] += xs;
                Xsl[(i0 + quad * 4 + r) * LSTR + tn * 16 + c] = f2bf(xs);
            }
        __syncthreads();

        #pragma unroll
        for (int k0 = 0; k0 < 64; k0 += 32) {
            bf16x8 af = *(const bf16x8*)&Xsl[(i0 + c) * LSTR + k0 + quad * 8];
            #pragma unroll
            for (int tn = 0; tn < 4; ++tn) {
                bf16x8 bfg = *(const bf16x8*)&Vt[(tn * 16 + c) * LSTR + k0 + quad * 8];
                oacc[tn] = __builtin_amdgcn_mfma_f32_16x16x32_bf16(af, bfg, oacc[tn], 0, 0, 0);
            }
        }
    }

    #pragma unroll
    for (int r = 0; r < 4; ++r) {
        float s = dsum[r];
        s += __shfl_xor(s, 1);
        s += __shfl_xor(s, 2);
        s += __shfl_xor(s, 4);
        s += __shfl_xor(s, 8);
        dsum[r] = 1.0f / fmaxf(s, 1e-4f);
    }
    #pragma unroll
    for (int tn = 0; tn < 4; ++tn)
        #pragma unroll
        for (int r = 0; r < 4; ++r)
            ob[(i0 + quad * 4 + r) * DH + tn * 16 + c] = oacc[tn][r] * dsum[r];
}

extern "C" void kernel_launch(void* const* d_in, const int* in_sizes, int n_in,
                              void* d_out, int out_size, void* d_ws, size_t ws_size,
                              hipStream_t stream) {
    (void)in_sizes; (void)n_in; (void)out_size;
    const float* q = (const float*)d_in[0];
    const float* k = (const float*)d_in[1];
    const float* v = (const float*)d_in[2];
    float* o = (float*)d_out;

    const size_t elems = (size_t)BH_N * PER_BH;              // 4,194,304
    const size_t need  = 2 * elems * sizeof(unsigned short); // 16.78 MB

    if (ws_size >= need) {
        unsigned short* kfo = (unsigned short*)d_ws;
        unsigned short* vfo = kfo + elems;
        prepass_kernel<<<dim3(NT, BH_N), 256, 0, stream>>>(k, v, kfo, vfo);
        poly_attn_main<<<dim3(BH_N * S_LEN / BQ), 256, 0, stream>>>(q, kfo, vfo, o);
    } else {
        poly_attn_fallback<<<dim3(S_LEN / 64, BH_N), 256, 0, stream>>>(q, k, v, o);
    }
}